// Round 2
// baseline (240.235 us; speedup 1.0000x reference)
//
#include <hip/hip_runtime.h>

// LocalCAN: S=200, B=1024, H=128, W=3, fp32.
// out[s,b,:] = sum_w x[s+w,b,:] * softmax_w( sum_h sigmoid(x[s+w,b,h]) * k[w,h] )
// where x = inputs * mask[:,:,None], zero-padded past s=S-1.
// NOTE: out-of-range windows are ZERO vectors -> sigmoid(0)=0.5 -> their alpha
// is 0.5*sum(k[w]) and participates in the softmax denominator. Computing with
// v=0 reproduces this exactly.

#define S_DIM 200
#define B_DIM 1024
#define H_DIM 128
#define W_DIM 3

__global__ __launch_bounds__(256) void LocalCAN_kernel(
    const float* __restrict__ x,     // [S,B,H]
    const float* __restrict__ mask,  // [S,B]
    const float* __restrict__ ker,   // [W,H]
    float* __restrict__ out)         // [S,B,H]
{
    const int tid  = blockIdx.x * blockDim.x + threadIdx.x;
    const int wave = tid >> 6;                 // one wave per (s,b) row
    const int lane = tid & 63;
    if (wave >= S_DIM * B_DIM) return;
    const int s = wave / B_DIM;
    const int b = wave - s * B_DIM;
    const int h = lane * 2;                    // lane owns h, h+1 (float2)

    float2 xv[W_DIM];
    float  dot[W_DIM];

    #pragma unroll
    for (int w = 0; w < W_DIM; ++w) {
        const int sw = s + w;
        float2 v = make_float2(0.f, 0.f);
        if (sw < S_DIM) {
            const float m = mask[sw * B_DIM + b];          // wave-uniform broadcast
            const float2 in = *reinterpret_cast<const float2*>(
                &x[((size_t)sw * B_DIM + b) * H_DIM + h]); // coalesced 8B/lane
            v.x = in.x * m;
            v.y = in.y * m;
        }
        xv[w] = v;
        // sigmoid-gated partial dot with kernel row w
        const float s0 = 1.f / (1.f + __expf(-v.x));
        const float s1 = 1.f / (1.f + __expf(-v.y));
        const float2 kv = *reinterpret_cast<const float2*>(&ker[w * H_DIM + h]);
        float d = s0 * kv.x + s1 * kv.y;
        // wave-wide butterfly reduction (64 lanes)
        #pragma unroll
        for (int off = 32; off > 0; off >>= 1)
            d += __shfl_xor(d, off);
        dot[w] = d;
    }

    // 3-way softmax over the window axis
    const float mx = fmaxf(dot[0], fmaxf(dot[1], dot[2]));
    const float e0 = __expf(dot[0] - mx);
    const float e1 = __expf(dot[1] - mx);
    const float e2 = __expf(dot[2] - mx);
    const float inv = 1.f / (e0 + e1 + e2);
    const float a0 = e0 * inv, a1 = e1 * inv, a2 = e2 * inv;

    float2 o;
    o.x = xv[0].x * a0 + xv[1].x * a1 + xv[2].x * a2;
    o.y = xv[0].y * a0 + xv[1].y * a1 + xv[2].y * a2;
    *reinterpret_cast<float2*>(&out[((size_t)s * B_DIM + b) * H_DIM + h]) = o;
}

extern "C" void kernel_launch(void* const* d_in, const int* in_sizes, int n_in,
                              void* d_out, int out_size, void* d_ws, size_t ws_size,
                              hipStream_t stream) {
    const float* x    = (const float*)d_in[0];  // [S,B,H]
    const float* mask = (const float*)d_in[1];  // [S,B]
    const float* ker  = (const float*)d_in[2];  // [W,H]
    float* out = (float*)d_out;

    const int total_waves = S_DIM * B_DIM;          // 204800
    const int threads = 256;                        // 4 waves/block
    const int blocks = (total_waves * 64 + threads - 1) / threads;  // 51200
    LocalCAN_kernel<<<blocks, threads, 0, stream>>>(x, mask, ker, out);
}

// Round 6
// 190.194 us; speedup vs baseline: 1.2631x; 1.2631x over previous
//
#include <hip/hip_runtime.h>

// LocalCAN: S=200, B=1024, H=128, W=3, fp32.
// out[s,b,:] = sum_w x[s+w,b,:] * softmax_w( sum_h sigmoid(x[s+w,b,h]) * k[w,h] )
// x = inputs * mask[:,:,None], zero-padded past s=S-1 (zero rows contribute
// alpha = 0.5*sum(k[w]) via sigmoid(0)=0.5 — must be computed, not skipped).
//
// Strip-mined design (R3): wave = 4 b-values x 8-s strip. lane = (bsub, hgrp).
// Each lane owns 8 h-elements (float4 at h0 and h0+64). Per row: sigmoid ONCE,
// 3 partial dots, one 16-lane 4-step butterfly reducing 4 rows at a time.
// 3-deep register ring over s, fully unrolled (compile-time ring indices).

#define S_DIM 200
#define B_DIM 1024
#define H_DIM 128
#define R_STRIP 8
#define BGRPS (B_DIM / 4)            // 256 b-groups of 4
#define STRIPS (S_DIM / R_STRIP)     // 25

__device__ __forceinline__ float fast_rcp(float v) {
    return __builtin_amdgcn_rcpf(v);
}

__global__ __launch_bounds__(256) void LocalCAN_kernel(
    const float* __restrict__ x,     // [S,B,H]
    const float* __restrict__ mask,  // [S,B]
    const float* __restrict__ ker,   // [3,H]
    float* __restrict__ out)         // [S,B,H]
{
    const int wave = (blockIdx.x * blockDim.x + threadIdx.x) >> 6;
    const int lane = threadIdx.x & 63;
    const int bgrp  = wave % BGRPS;
    const int strip = wave / BGRPS;
    if (strip >= STRIPS) return;

    const int bsub = lane >> 4;        // 0..3  (which b of the group)
    const int hg   = lane & 15;        // 0..15 (h-group within the row)
    const int b    = bgrp * 4 + bsub;
    const int h0   = hg * 4;           // float4 #1 at h0, #2 at h0+64
    const int s0   = strip * R_STRIP;

    // conv kernel rows, lane's 8 h-slots (loaded once; L1/L2-hot, 1.5 KB total)
    float kr[3][8];
    #pragma unroll
    for (int w = 0; w < 3; ++w) {
        const float4 ka = *reinterpret_cast<const float4*>(&ker[w * H_DIM + h0]);
        const float4 kb = *reinterpret_cast<const float4*>(&ker[w * H_DIM + 64 + h0]);
        kr[w][0] = ka.x; kr[w][1] = ka.y; kr[w][2] = ka.z; kr[w][3] = ka.w;
        kr[w][4] = kb.x; kr[w][5] = kb.y; kr[w][6] = kb.z; kr[w][7] = kb.w;
    }

    float xr[3][8];   // ring: masked x rows
    float dr[3][3];   // ring: dots of row r with kernel rows 0..2

    #pragma unroll
    for (int i = 0; i < R_STRIP + 2; ++i) {      // rows s0 .. s0+9
        const int r    = s0 + i;
        const int slot = i % 3;                  // compile-time under unroll

        float v[8];
        if (r < S_DIM) {
            const float m = mask[r * B_DIM + b];             // 16-way broadcast
            const size_t base = ((size_t)r * B_DIM + b) * H_DIM;
            const float4 va = *reinterpret_cast<const float4*>(&x[base + h0]);
            const float4 vb = *reinterpret_cast<const float4*>(&x[base + 64 + h0]);
            v[0] = va.x * m; v[1] = va.y * m; v[2] = va.z * m; v[3] = va.w * m;
            v[4] = vb.x * m; v[5] = vb.y * m; v[6] = vb.z * m; v[7] = vb.w * m;
        } else {
            #pragma unroll
            for (int j = 0; j < 8; ++j) v[j] = 0.f;          // zero-pad row
        }

        // sigmoid once per element + 3 partial dots
        float p0 = 0.f, p1 = 0.f, p2 = 0.f;
        #pragma unroll
        for (int j = 0; j < 8; ++j) {
            const float sg = fast_rcp(1.f + __expf(-v[j]));
            p0 += sg * kr[0][j];
            p1 += sg * kr[1][j];
            p2 += sg * kr[2][j];
            xr[slot][j] = v[j];
        }
        // 16-lane butterfly (xor 1,2,4,8) — reduces all 4 b-rows of the wave
        // in the same instruction stream (3 shuffles/row amortized vs 18 before)
        #pragma unroll
        for (int off = 1; off < 16; off <<= 1) {
            p0 += __shfl_xor(p0, off);
            p1 += __shfl_xor(p1, off);
            p2 += __shfl_xor(p2, off);
        }
        dr[slot][0] = p0; dr[slot][1] = p1; dr[slot][2] = p2;

        if (i >= 2) {
            const int so  = r - 2;                // output row (always < S)
            const int sA  = (i - 2) % 3;          // row so   -> window 0
            const int sB  = (i - 1) % 3;          // row so+1 -> window 1
            const int sC  = slot;                 // row so+2 -> window 2
            const float d0 = dr[sA][0], d1 = dr[sB][1], d2 = dr[sC][2];
            const float mx = fmaxf(d0, fmaxf(d1, d2));
            const float e0 = __expf(d0 - mx);
            const float e1 = __expf(d1 - mx);
            const float e2 = __expf(d2 - mx);
            const float inv = fast_rcp(e0 + e1 + e2);
            const float a0 = e0 * inv, a1 = e1 * inv, a2 = e2 * inv;

            float o[8];
            #pragma unroll
            for (int j = 0; j < 8; ++j)
                o[j] = xr[sA][j] * a0 + xr[sB][j] * a1 + xr[sC][j] * a2;

            const size_t obase = ((size_t)so * B_DIM + b) * H_DIM;
            *reinterpret_cast<float4*>(&out[obase + h0]) =
                make_float4(o[0], o[1], o[2], o[3]);
            *reinterpret_cast<float4*>(&out[obase + 64 + h0]) =
                make_float4(o[4], o[5], o[6], o[7]);
        }
    }
}

extern "C" void kernel_launch(void* const* d_in, const int* in_sizes, int n_in,
                              void* d_out, int out_size, void* d_ws, size_t ws_size,
                              hipStream_t stream) {
    const float* x    = (const float*)d_in[0];  // [S,B,H]
    const float* mask = (const float*)d_in[1];  // [S,B]
    const float* ker  = (const float*)d_in[2];  // [3,H]
    float* out = (float*)d_out;

    const int total_waves = BGRPS * STRIPS;     // 6400
    const int threads = 256;                    // 4 waves/block
    const int blocks = (total_waves * 64 + threads - 1) / threads;  // 1600
    LocalCAN_kernel<<<blocks, threads, 0, stream>>>(x, mask, ker, out);
}

// Round 8
// 188.174 us; speedup vs baseline: 1.2767x; 1.0107x over previous
//
#include <hip/hip_runtime.h>

// LocalCAN: S=200, B=1024, H=128, W=3, fp32.
// out[s,b,:] = sum_w x[s+w,b,:] * softmax_w( sum_h sigmoid(x[s+w,b,h]) * k[w,h] )
// x = inputs * mask[:,:,None], zero-padded past s=S-1 (zero rows contribute
// alpha = 0.5*sum(k[w]) via sigmoid(0)=0.5 — must be computed, not skipped).
//
// R7: latency-bound fix. Wave = 2 b-values x 32 h-lanes (1 float4/lane/row;
// wave row-load = one contiguous 1KB segment), R_STRIP=4 -> 25600 waves
// (4x R6) for TLP. All 6 row-loads issued up front for MLP. Butterfly is
// 5 steps over the 32 hg-lanes, reducing both b-rows per instruction.

#define S_DIM 200
#define B_DIM 1024
#define H_DIM 128
#define R_STRIP 4
#define ROWS (R_STRIP + 2)           // 6 rows loaded per strip
#define BGRPS (B_DIM / 2)            // 512 b-groups of 2
#define STRIPS (S_DIM / R_STRIP)     // 50

__device__ __forceinline__ float fast_rcp(float v) {
    return __builtin_amdgcn_rcpf(v);
}

__global__ __launch_bounds__(256) void LocalCAN_kernel(
    const float* __restrict__ x,     // [S,B,H]
    const float* __restrict__ mask,  // [S,B]
    const float* __restrict__ ker,   // [3,H]
    float* __restrict__ out)         // [S,B,H]
{
    const int wave  = (blockIdx.x * blockDim.x + threadIdx.x) >> 6;
    const int lane  = threadIdx.x & 63;
    const int bgrp  = wave % BGRPS;
    const int strip = wave / BGRPS;          // < STRIPS (grid exact)

    const int bsub = lane >> 5;              // 0..1
    const int hg   = lane & 31;              // 0..31
    const int b    = bgrp * 2 + bsub;
    const int h0   = hg * 4;                 // one float4 covers lane's h-slice
    const int s0   = strip * R_STRIP;

    // conv kernel rows for this lane's h-slice (L1-hot, 1.5 KB total)
    float kr[3][4];
    #pragma unroll
    for (int w = 0; w < 3; ++w) {
        const float4 k4 = *reinterpret_cast<const float4*>(&ker[w * H_DIM + h0]);
        kr[w][0] = k4.x; kr[w][1] = k4.y; kr[w][2] = k4.z; kr[w][3] = k4.w;
    }

    // ---- load phase: all 6 rows issued up front (deep MLP) ----
    float v[ROWS][4];
    #pragma unroll
    for (int i = 0; i < ROWS; ++i) {
        const int r = s0 + i;
        if (r < S_DIM) {                     // wave-uniform; false only in last strip
            const float m = mask[r * B_DIM + b];
            const float4 t = *reinterpret_cast<const float4*>(
                &x[((size_t)r * B_DIM + b) * H_DIM + h0]);
            v[i][0] = t.x * m; v[i][1] = t.y * m;
            v[i][2] = t.z * m; v[i][3] = t.w * m;
        } else {
            v[i][0] = v[i][1] = v[i][2] = v[i][3] = 0.f;
        }
    }

    // ---- dot phase: sigmoid once/element, 3 partial dots, 5-step butterfly ----
    float d[ROWS][3];
    #pragma unroll
    for (int i = 0; i < ROWS; ++i) {
        float p0 = 0.f, p1 = 0.f, p2 = 0.f;
        #pragma unroll
        for (int j = 0; j < 4; ++j) {
            const float sg = fast_rcp(1.f + __expf(-v[i][j]));
            p0 += sg * kr[0][j];
            p1 += sg * kr[1][j];
            p2 += sg * kr[2][j];
        }
        #pragma unroll
        for (int off = 1; off < 32; off <<= 1) {   // reduces both b-rows at once
            p0 += __shfl_xor(p0, off);
            p1 += __shfl_xor(p1, off);
            p2 += __shfl_xor(p2, off);
        }
        d[i][0] = p0; d[i][1] = p1; d[i][2] = p2;
    }

    // ---- output phase: 3-way softmax + weighted sum, 4 rows ----
    #pragma unroll
    for (int o = 0; o < R_STRIP; ++o) {
        const float d0 = d[o][0], d1 = d[o + 1][1], d2 = d[o + 2][2];
        const float mx = fmaxf(d0, fmaxf(d1, d2));
        const float e0 = __expf(d0 - mx);
        const float e1 = __expf(d1 - mx);
        const float e2 = __expf(d2 - mx);
        const float inv = fast_rcp(e0 + e1 + e2);
        const float a0 = e0 * inv, a1 = e1 * inv, a2 = e2 * inv;

        float4 ov;
        ov.x = v[o][0] * a0 + v[o + 1][0] * a1 + v[o + 2][0] * a2;
        ov.y = v[o][1] * a0 + v[o + 1][1] * a1 + v[o + 2][1] * a2;
        ov.z = v[o][2] * a0 + v[o + 1][2] * a1 + v[o + 2][2] * a2;
        ov.w = v[o][3] * a0 + v[o + 1][3] * a1 + v[o + 2][3] * a2;

        *reinterpret_cast<float4*>(
            &out[((size_t)(s0 + o) * B_DIM + b) * H_DIM + h0]) = ov;
    }
}

extern "C" void kernel_launch(void* const* d_in, const int* in_sizes, int n_in,
                              void* d_out, int out_size, void* d_ws, size_t ws_size,
                              hipStream_t stream) {
    const float* x    = (const float*)d_in[0];  // [S,B,H]
    const float* mask = (const float*)d_in[1];  // [S,B]
    const float* ker  = (const float*)d_in[2];  // [3,H]
    float* out = (float*)d_out;

    const int total_waves = BGRPS * STRIPS;     // 25600
    const int threads = 256;                    // 4 waves/block
    const int blocks = (total_waves * 64 + threads - 1) / threads;  // 6400
    LocalCAN_kernel<<<blocks, threads, 0, stream>>>(x, mask, ker, out);
}